// Round 4
// baseline (183.676 us; speedup 1.0000x reference)
//
#include <hip/hip_runtime.h>
#include <hip/hip_bf16.h>

// Problem constants: N=1024, C=32, T=8, V=64, K=3, CT=256
// out[n][c][v][t] = sum_k sum_j W[k][c*8+t][j] * U_k[j][v] + bias2T[c*8+t][v]
// U_k[j][v] = sum_u x[n][j][u] * A[k][u][v]
//
// R4: 256-thr blocks, 2 blocks per n (each redundantly computes U; stage-1 is
// only 20% of FLOPs). Wave owns 32 output rows (acc2=32 AGPR) + stage-1 in two
// halves (acc1=32 AGPR reused). xf NOT register-resident (reloaded per k from
// L2) -> peak ~73 VGPR + 64 AGPR, fits (256,3)=170 budget -> 3 blocks/CU, no
// spill. aw (Wsw) prefetched across the barrier, depth-2 rotation.
// R2/R3 lesson: accumulator footprint must fit the waves/EU budget HONESTLY;
// any cap below liveness = scratch spill = +30..110 MB WRITE_SIZE regression.

typedef __attribute__((ext_vector_type(8))) short bf16x8;
typedef __attribute__((ext_vector_type(4))) float f32x4;

__device__ __forceinline__ short f2bf(float f) {
  union { float f; unsigned u; } c; c.f = f;
  unsigned r = c.u + 0x7FFFu + ((c.u >> 16) & 1u);   // RNE
  return (short)(r >> 16);
}

__device__ __forceinline__ unsigned pkbf(float a, float b) {
  float2 t; t.x = a; t.y = b;
  union { __hip_bfloat162 h; unsigned u; } c;
  c.h = __float22bfloat162_rn(t);   // v_cvt_pk_bf16_f32, RNE
  return c.u;
}

// ---------------- workspace layout (bytes) ----------------
// Wsw   : short[196608] @ 0        fragment-ordered W  (k,hw8,mt,ks,lane,e)
// Asw   : short[12288]  @ 393216   fragment-ordered A^T (k,ks,nt,lane,e)
// biasCM: float[16384]  @ 417792   column-major bias: biasCM[w*256 + d]
#define ASW_OFF  393216
#define BIAS_OFF 417792

__global__ __launch_bounds__(256) void prep_kernel(
    const float* __restrict__ W, const float* __restrict__ b,
    const float* __restrict__ A, short* __restrict__ Wsw,
    short* __restrict__ Asw, float* __restrict__ biasCM) {
  int t = blockIdx.x * 256 + threadIdx.x;
  if (t < 196608) {
    // Wsw flat = ((((k*8+hw)*2+mt)*8+ks)*64 + lane)*8 + e
    int e = t & 7, l = (t >> 3) & 63, ks = (t >> 9) & 7, mt = (t >> 12) & 1,
        hw = (t >> 13) & 7, k = t >> 16;
    int d = 32 * hw + 16 * mt + (l & 15);
    int c = 32 * ks + 8 * (l >> 4) + e;
    Wsw[t] = f2bf(W[(k * 256 + d) * 256 + c]);
  } else if (t < 196608 + 12288) {
    // Asw flat = (((k*2+ks)*4+nt)*64 + lane)*8 + e ; value = A[k][v][w]
    int t2 = t - 196608;
    int e = t2 & 7, l = (t2 >> 3) & 63, nt = (t2 >> 9) & 3, ks = (t2 >> 11) & 1,
        k = t2 >> 12;
    int w = nt * 16 + (l & 15);
    int v = ks * 32 + (l >> 4) * 8 + e;
    Asw[t2] = f2bf(A[(k * 64 + v) * 64 + w]);
  } else {
    // biasCM[w*256 + d] = sum_k (sum_v A[k][v][w]) * b[k][d]
    int t2 = t - 196608 - 12288;
    int w = t2 >> 8, d = t2 & 255;
    float s = 0.f;
    for (int k = 0; k < 3; ++k) {
      float cs = 0.f;
#pragma unroll
      for (int v = 0; v < 64; ++v) cs += A[(k * 64 + v) * 64 + w];
      s += cs * b[k * 256 + d];
    }
    biasCM[t2] = s;
  }
}

#define UT_STRIDE 264  // bf16 elems per Ut row (256 + 8 pad), 528B rows, 16B-aligned

__global__ __launch_bounds__(256, 3) void gcn_main(
    const float* __restrict__ x, const short* __restrict__ Wsw,
    const short* __restrict__ Asw, const float* __restrict__ biasCM,
    float* __restrict__ out) {
  __shared__ short Ut[64 * UT_STRIDE];  // Ut[w][ct] = U[ct][w], 33792 B

  const int tid = threadIdx.x;
  const int wv = tid >> 6;        // wave 0..3
  const int lane = tid & 63;
  const int li = lane & 15;
  const int lq = lane >> 4;

  // sibling-pair swizzle: blocks g and g+8 are (n,half=0/1) -> same XCD
  const int g = blockIdx.x;
  const int n = (g & 7) | ((g >> 4) << 3);
  const int half = (g >> 3) & 1;
  const int hw = half * 4 + wv;   // stage-2 row-block 0..7 (d base = 32*hw)

  const float* xn = x + (size_t)n * 16384;
  float* outn = out + (size_t)n * 16384;

  // ---- acc2 init = bias (epilogue becomes a pure store); biasCM is L2-hot
  f32x4 acc2[2][4];
#pragma unroll
  for (int mt = 0; mt < 2; ++mt)
#pragma unroll
    for (int nt = 0; nt < 4; ++nt) {
      const float4 bb = *(const float4*)(biasCM + (nt * 16 + li) * 256 +
                                         32 * hw + 16 * mt + 4 * lq);
      acc2[mt][nt] = (f32x4){bb.x, bb.y, bb.z, bb.w};
    }

#pragma unroll
  for (int k = 0; k < 3; ++k) {
    const short* AswK = Asw + k * 4096;

    // ---------- stage 1: this wave computes U_k rows [64wv, 64wv+64) ----------
    // two halves of 32 rows; xf reloaded per half (x L2-hot after k=0) so it
    // is never live across stage 2 -> keeps stage-2 peak VGPRs low.
#pragma unroll
    for (int h = 0; h < 2; ++h) {
      bf16x8 xfh[2][2];
#pragma unroll
      for (int ks = 0; ks < 2; ++ks)
#pragma unroll
        for (int m2 = 0; m2 < 2; ++m2) {
          const float4* p = (const float4*)(
              xn + (64 * wv + 16 * (2 * h + m2) + li) * 64 + 32 * ks + 8 * lq);
          float4 f0 = p[0], f1 = p[1];
          union { bf16x8 v; unsigned u[4]; } t;
          t.u[0] = pkbf(f0.x, f0.y); t.u[1] = pkbf(f0.z, f0.w);
          t.u[2] = pkbf(f1.x, f1.y); t.u[3] = pkbf(f1.z, f1.w);
          xfh[ks][m2] = t.v;
        }

      f32x4 acc1[2][4];
#pragma unroll
      for (int m2 = 0; m2 < 2; ++m2)
#pragma unroll
        for (int nt = 0; nt < 4; ++nt)
          acc1[m2][nt] = (f32x4){0.f, 0.f, 0.f, 0.f};

#pragma unroll
      for (int ks = 0; ks < 2; ++ks) {
        bf16x8 bfr[4];
#pragma unroll
        for (int nt = 0; nt < 4; ++nt)
          bfr[nt] = *(const bf16x8*)(AswK + ((ks * 4 + nt) * 64 + lane) * 8);
#pragma unroll
        for (int m2 = 0; m2 < 2; ++m2)
#pragma unroll
          for (int nt = 0; nt < 4; ++nt)
            acc1[m2][nt] = __builtin_amdgcn_mfma_f32_16x16x32_bf16(
                xfh[ks][m2], bfr[nt], acc1[m2][nt], 0, 0, 0);
      }

      // write U_k -> Ut transposed (prev k's readers drained by end-of-k barrier)
#pragma unroll
      for (int m2 = 0; m2 < 2; ++m2)
#pragma unroll
        for (int nt = 0; nt < 4; ++nt) {
          int w = nt * 16 + li;
          int ct = 64 * wv + 16 * (2 * h + m2) + 4 * lq;
          union { unsigned u[2]; unsigned long long ull; } p;
          p.u[0] = pkbf(acc1[m2][nt][0], acc1[m2][nt][1]);
          p.u[1] = pkbf(acc1[m2][nt][2], acc1[m2][nt][3]);
          *(unsigned long long*)(&Ut[w * UT_STRIDE + ct]) = p.ull;
        }
    }

    // ---------- stage 2: acc2 += W_k[rows 32hw..32hw+32) @ U_k ----------
    const short* WswK = Wsw + (k * 8 + hw) * 8192;

    // prefetch aw for ks=0,1 BEFORE the barrier (no Ut dependency):
    // their L2 latency is absorbed by the barrier wait.
    bf16x8 awA[2], awB[2];
#pragma unroll
    for (int mt = 0; mt < 2; ++mt) {
      awA[mt] = *(const bf16x8*)(WswK + ((mt * 8 + 0) * 64 + lane) * 8);
      awB[mt] = *(const bf16x8*)(WswK + ((mt * 8 + 1) * 64 + lane) * 8);
    }

    __syncthreads();  // Ut ready for all waves

#pragma unroll
    for (int ks = 0; ks < 8; ++ks) {
      bf16x8 bu[4];
#pragma unroll
      for (int nt = 0; nt < 4; ++nt)
        bu[nt] = *(const bf16x8*)(&Ut[(nt * 16 + li) * UT_STRIDE + 32 * ks + 8 * lq]);

      bf16x8 aw0 = (ks & 1) ? awB[0] : awA[0];
      bf16x8 aw1 = (ks & 1) ? awB[1] : awA[1];
      if (ks + 2 < 8) {  // depth-2 rotate: refill the slot just consumed
#pragma unroll
        for (int mt = 0; mt < 2; ++mt) {
          bf16x8 nv = *(const bf16x8*)(WswK + ((mt * 8 + ks + 2) * 64 + lane) * 8);
          if (ks & 1) awB[mt] = nv; else awA[mt] = nv;
        }
      }

#pragma unroll
      for (int nt = 0; nt < 4; ++nt)
        acc2[0][nt] = __builtin_amdgcn_mfma_f32_16x16x32_bf16(
            aw0, bu[nt], acc2[0][nt], 0, 0, 0);
#pragma unroll
      for (int nt = 0; nt < 4; ++nt)
        acc2[1][nt] = __builtin_amdgcn_mfma_f32_16x16x32_bf16(
            aw1, bu[nt], acc2[1][nt], 0, 0, 0);
    }

    if (k < 2) __syncthreads();  // all Ut reads done before next k's writes
  }

  // ---------- epilogue: direct float4 stores from C-layout ----------
  // d = 32hw+16mt+4lq+r = 128half+32wv+16mt+4lq+r
  // -> c = 16half+4wv+2mt+(lq>>1), t = 4(lq&1)+r, w = 16nt+li
#pragma unroll
  for (int mt = 0; mt < 2; ++mt)
#pragma unroll
    for (int nt = 0; nt < 4; ++nt) {
      float4 vv;
      vv.x = acc2[mt][nt][0];
      vv.y = acc2[mt][nt][1];
      vv.z = acc2[mt][nt][2];
      vv.w = acc2[mt][nt][3];
      *(float4*)(outn + (16 * half + 4 * wv + 2 * mt + (lq >> 1)) * 512 +
                 (nt * 16 + li) * 8 + 4 * (lq & 1)) = vv;
    }
}

extern "C" void kernel_launch(void* const* d_in, const int* in_sizes, int n_in,
                              void* d_out, int out_size, void* d_ws, size_t ws_size,
                              hipStream_t stream) {
  (void)in_sizes; (void)n_in; (void)out_size; (void)ws_size;
  const float* x = (const float*)d_in[0];
  const float* W = (const float*)d_in[1];
  const float* b = (const float*)d_in[2];
  const float* A = (const float*)d_in[3];
  float* out = (float*)d_out;

  short* Wsw = (short*)d_ws;
  short* Asw = (short*)((char*)d_ws + ASW_OFF);
  float* biasCM = (float*)((char*)d_ws + BIAS_OFF);

  // prep: 196608 (W) + 12288 (A) + 16384 (bias) = 225280 threads = 880 blocks
  prep_kernel<<<880, 256, 0, stream>>>(W, b, A, Wsw, Asw, biasCM);
  gcn_main<<<2048, 256, 0, stream>>>(x, Wsw, Asw, biasCM, out);
}

// Round 5
// 147.022 us; speedup vs baseline: 1.2493x; 1.2493x over previous
//
#include <hip/hip_runtime.h>
#include <hip/hip_bf16.h>

// Problem constants: N=1024, C=32, T=8, V=64, K=3, CT=256
// out[n][c][v][t] = sum_k sum_j W[k][c*8+t][j] * U_k[j][v] + bias2T[c*8+t][v]
// U_k[j][v] = sum_u x[n][j][u] * A[k][u][v]
//
// R5: R1 work-minimal structure (1 block/n, 4 waves, wave owns 64 rows, xf
// register-resident) + double-buffered Ut -> 3 barriers/block instead of 6,
// stage1(k+1) overlaps stage2(k). LDS 67.6KB caps us at 2 blocks/CU, so the
// 2-waves/SIMD register budget is 256 -> xf + acc1 + acc2 all live is fine
// (R1: 252 regs, no spill). aw rotate-prefetch crosses the barrier (refill
// ks=6,7 from next k's slice) so post-barrier MFMAs never wait on L2.
// R2/R3 lesson: never cap regs below liveness (spill = +30..110MB WRITE_SIZE).
// R4 lesson: occupancy bought with redundant work regresses; barriers are the
// real limiter.

typedef __attribute__((ext_vector_type(8))) short bf16x8;
typedef __attribute__((ext_vector_type(4))) float f32x4;

__device__ __forceinline__ short f2bf(float f) {
  union { float f; unsigned u; } c; c.f = f;
  unsigned r = c.u + 0x7FFFu + ((c.u >> 16) & 1u);   // RNE
  return (short)(r >> 16);
}

__device__ __forceinline__ unsigned pkbf(float a, float b) {
  float2 t; t.x = a; t.y = b;
  union { __hip_bfloat162 h; unsigned u; } c;
  c.h = __float22bfloat162_rn(t);   // v_cvt_pk_bf16_f32, RNE
  return c.u;
}

// ---------------- workspace layout (bytes) ----------------
// Wsw   : short[196608] @ 0        fragment-ordered W  (k,wv4,mt4,ks8,lane,e)
// Asw   : short[12288]  @ 393216   fragment-ordered A^T (k,ks,nt,lane,e)
// biasCM: float[16384]  @ 417792   column-major bias: biasCM[w*256 + d]
#define ASW_OFF  393216
#define BIAS_OFF 417792

__global__ __launch_bounds__(256) void prep_kernel(
    const float* __restrict__ W, const float* __restrict__ b,
    const float* __restrict__ A, short* __restrict__ Wsw,
    short* __restrict__ Asw, float* __restrict__ biasCM) {
  int t = blockIdx.x * 256 + threadIdx.x;
  if (t < 196608) {
    // Wsw flat = ((((k*4+wv)*4+mt)*8+ks)*64 + lane)*8 + e
    int e = t & 7, l = (t >> 3) & 63, ks = (t >> 9) & 7, mt = (t >> 12) & 3,
        wv = (t >> 14) & 3, k = t >> 16;
    int d = 64 * wv + 16 * mt + (l & 15);
    int c = 32 * ks + 8 * (l >> 4) + e;
    Wsw[t] = f2bf(W[(k * 256 + d) * 256 + c]);
  } else if (t < 196608 + 12288) {
    // Asw flat = (((k*2+ks)*4+nt)*64 + lane)*8 + e ; value = A[k][v][w]
    int t2 = t - 196608;
    int e = t2 & 7, l = (t2 >> 3) & 63, nt = (t2 >> 9) & 3, ks = (t2 >> 11) & 1,
        k = t2 >> 12;
    int w = nt * 16 + (l & 15);
    int v = ks * 32 + (l >> 4) * 8 + e;
    Asw[t2] = f2bf(A[(k * 64 + v) * 64 + w]);
  } else {
    // biasCM[w*256 + d] = sum_k (sum_v A[k][v][w]) * b[k][d]
    int t2 = t - 196608 - 12288;
    int w = t2 >> 8, d = t2 & 255;
    float s = 0.f;
    for (int k = 0; k < 3; ++k) {
      float cs = 0.f;
#pragma unroll
      for (int v = 0; v < 64; ++v) cs += A[(k * 64 + v) * 64 + w];
      s += cs * b[k * 256 + d];
    }
    biasCM[t2] = s;
  }
}

#define UT_STRIDE 264  // bf16 elems per Ut row (256 + 8 pad), 528B rows

// stage-1: compute U_k rows [64wv, 64wv+64), write transposed into Utw
__device__ __forceinline__ void stage1(
    const short* __restrict__ Asw, int k, const bf16x8 (&xf)[2][4],
    short* __restrict__ Utw, int wv, int lane, int li, int lq) {
  const short* AswK = Asw + k * 4096;
  f32x4 acc1[4][4];
#pragma unroll
  for (int mt = 0; mt < 4; ++mt)
#pragma unroll
    for (int nt = 0; nt < 4; ++nt)
      acc1[mt][nt] = (f32x4){0.f, 0.f, 0.f, 0.f};

#pragma unroll
  for (int ks = 0; ks < 2; ++ks) {
    bf16x8 bfr[4];
#pragma unroll
    for (int nt = 0; nt < 4; ++nt)
      bfr[nt] = *(const bf16x8*)(AswK + ((ks * 4 + nt) * 64 + lane) * 8);
#pragma unroll
    for (int mt = 0; mt < 4; ++mt)
#pragma unroll
      for (int nt = 0; nt < 4; ++nt)
        acc1[mt][nt] = __builtin_amdgcn_mfma_f32_16x16x32_bf16(
            xf[ks][mt], bfr[nt], acc1[mt][nt], 0, 0, 0);
  }

#pragma unroll
  for (int mt = 0; mt < 4; ++mt)
#pragma unroll
    for (int nt = 0; nt < 4; ++nt) {
      int w = nt * 16 + li;
      int ct = 64 * wv + 16 * mt + 4 * lq;
      union { unsigned u[2]; unsigned long long ull; } p;
      p.u[0] = pkbf(acc1[mt][nt][0], acc1[mt][nt][1]);
      p.u[1] = pkbf(acc1[mt][nt][2], acc1[mt][nt][3]);
      *(unsigned long long*)(&Utw[w * UT_STRIDE + ct]) = p.ull;
    }
}

__global__ __launch_bounds__(256, 2) void gcn_main(
    const float* __restrict__ x, const short* __restrict__ Wsw,
    const short* __restrict__ Asw, const float* __restrict__ biasCM,
    float* __restrict__ out) {
  __shared__ short UtA[64 * UT_STRIDE];  // 33792 B each; 67584 total
  __shared__ short UtB[64 * UT_STRIDE];

  const int tid = threadIdx.x;
  const int wv = tid >> 6;        // wave 0..3, owns rows [64wv, 64wv+64)
  const int lane = tid & 63;
  const int li = lane & 15;
  const int lq = lane >> 4;
  const int n = blockIdx.x;

  const float* xn = x + (size_t)n * 16384;
  float* outn = out + (size_t)n * 16384;

  // ---- acc2 init = bias (epilogue becomes a pure store); biasCM is L2-hot
  f32x4 acc2[4][4];
#pragma unroll
  for (int mt = 0; mt < 4; ++mt)
#pragma unroll
    for (int nt = 0; nt < 4; ++nt) {
      const float4 bb = *(const float4*)(biasCM + (nt * 16 + li) * 256 +
                                         64 * wv + 16 * mt + 4 * lq);
      acc2[mt][nt] = (f32x4){bb.x, bb.y, bb.z, bb.w};
    }

  // ---- stage-1 A-operand: wave's 64x64 block of Xn, registers, k-invariant
  bf16x8 xf[2][4];
#pragma unroll
  for (int ks = 0; ks < 2; ++ks)
#pragma unroll
    for (int mt = 0; mt < 4; ++mt) {
      const float4* p =
          (const float4*)(xn + (64 * wv + 16 * mt + li) * 64 + 32 * ks + 8 * lq);
      float4 f0 = p[0], f1 = p[1];
      union { bf16x8 v; unsigned u[4]; } t;
      t.u[0] = pkbf(f0.x, f0.y); t.u[1] = pkbf(f0.z, f0.w);
      t.u[2] = pkbf(f1.x, f1.y); t.u[3] = pkbf(f1.z, f1.w);
      xf[ks][mt] = t.v;
    }

  // ---- preamble: U_0 -> UtA; prefetch aw(k=0, ks=0,1) before the barrier
  stage1(Asw, 0, xf, UtA, wv, lane, li, lq);

  bf16x8 awA[4], awB[4];
  {
    const short* W0 = Wsw + (0 * 4 + wv) * 16384;
#pragma unroll
    for (int mt = 0; mt < 4; ++mt) {
      awA[mt] = *(const bf16x8*)(W0 + ((mt * 8 + 0) * 64 + lane) * 8);
      awB[mt] = *(const bf16x8*)(W0 + ((mt * 8 + 1) * 64 + lane) * 8);
    }
  }

  __syncthreads();  // UtA complete

#pragma unroll
  for (int k = 0; k < 3; ++k) {
    const short* Utr = (k & 1) ? UtB : UtA;
    short* Utw = (k & 1) ? UtA : UtB;
    const short* WswK = Wsw + (k * 4 + wv) * 16384;
    const short* WswN = Wsw + ((k + 1) * 4 + wv) * 16384;  // next k (k<2 only)

    // ---------- stage 2: acc2 += W_k[rows 64wv..] @ U_k (from Utr) ----------
#pragma unroll
    for (int ks = 0; ks < 8; ++ks) {
      bf16x8 bu[4];
#pragma unroll
      for (int nt = 0; nt < 4; ++nt)
        bu[nt] = *(const bf16x8*)(&Utr[(nt * 16 + li) * UT_STRIDE + 32 * ks + 8 * lq]);

      bf16x8 aw0[4];
#pragma unroll
      for (int mt = 0; mt < 4; ++mt) aw0[mt] = (ks & 1) ? awB[mt] : awA[mt];

      // depth-2 rotate; at ks=6,7 refill from NEXT k's slice (crosses barrier)
      if (ks < 6) {
#pragma unroll
        for (int mt = 0; mt < 4; ++mt) {
          bf16x8 nv = *(const bf16x8*)(WswK + ((mt * 8 + ks + 2) * 64 + lane) * 8);
          if (ks & 1) awB[mt] = nv; else awA[mt] = nv;
        }
      } else if (k < 2) {
#pragma unroll
        for (int mt = 0; mt < 4; ++mt) {
          bf16x8 nv = *(const bf16x8*)(WswN + ((mt * 8 + (ks - 6)) * 64 + lane) * 8);
          if (ks & 1) awB[mt] = nv; else awA[mt] = nv;
        }
      }

#pragma unroll
      for (int mt = 0; mt < 4; ++mt)
#pragma unroll
        for (int nt = 0; nt < 4; ++nt)
          acc2[mt][nt] = __builtin_amdgcn_mfma_f32_16x16x32_bf16(
              aw0[mt], bu[nt], acc2[mt][nt], 0, 0, 0);
    }

    // ---------- stage 1 of k+1 into the other buffer (no conflict: its
    // previous readers finished before the barrier that opened this superstep)
    if (k < 2) {
      stage1(Asw, k + 1, xf, Utw, wv, lane, li, lq);
      __syncthreads();  // Utw complete; also fences this superstep's Utr reads
    }
  }

  // ---------- epilogue: direct float4 stores from C-layout ----------
  // d = 64wv+16mt+4lq+r -> c = 8wv+2mt+(lq>>1), t = 4(lq&1)+r, w = 16nt+li
#pragma unroll
  for (int mt = 0; mt < 4; ++mt)
#pragma unroll
    for (int nt = 0; nt < 4; ++nt) {
      float4 vv;
      vv.x = acc2[mt][nt][0];
      vv.y = acc2[mt][nt][1];
      vv.z = acc2[mt][nt][2];
      vv.w = acc2[mt][nt][3];
      *(float4*)(outn + (8 * wv + 2 * mt + (lq >> 1)) * 512 +
                 (nt * 16 + li) * 8 + 4 * (lq & 1)) = vv;
    }
}

extern "C" void kernel_launch(void* const* d_in, const int* in_sizes, int n_in,
                              void* d_out, int out_size, void* d_ws, size_t ws_size,
                              hipStream_t stream) {
  (void)in_sizes; (void)n_in; (void)out_size; (void)ws_size;
  const float* x = (const float*)d_in[0];
  const float* W = (const float*)d_in[1];
  const float* b = (const float*)d_in[2];
  const float* A = (const float*)d_in[3];
  float* out = (float*)d_out;

  short* Wsw = (short*)d_ws;
  short* Asw = (short*)((char*)d_ws + ASW_OFF);
  float* biasCM = (float*)((char*)d_ws + BIAS_OFF);

  // prep: 196608 (W) + 12288 (A) + 16384 (bias) = 225280 threads = 880 blocks
  prep_kernel<<<880, 256, 0, stream>>>(W, b, A, Wsw, Asw, biasCM);
  gcn_main<<<1024, 256, 0, stream>>>(x, Wsw, Asw, biasCM, out);
}